// Round 10
// baseline (2586.461 us; speedup 1.0000x reference)
//
#include <hip/hip_runtime.h>
#include <math.h>

// Problem constants (fixed by the reference)
#define HDIM   512
#define NDIM   16
#define SEQ    64
#define TSTEPS 63
#define BATCH  256
#define ODIM   9
#define NTHR   512

// R10: flags back to agent-scope atomics EVERYWHERE (R6/R7-proven); data
// exchange keeps R7's L2 fast path (plain store + sc0 load, co-XCD groups).
// R8/R9 hang diagnosis: sc0-load FLAG POLLING can hit a stale L1 line forever
// (first poll allocates the line before the producer's store lands in L2; no
// eviction pressure during the spin -> infinite loop). Data sc0 loads are
// safe: single read per round AFTER the flag barrier, and the 1MB weight
// stream flushes L1 every matvec. Atomics architecturally bypass L1.
// Kept from R8: folded g-publish, fewer barriers, float4 LDS g-reads, weight
// register prefetch (8 rows) overlapped with the z-wait.
// R5 lesson: 512 thr, launch_bounds(512,2), watch VGPR=128 budget.
//
// Encoder S4 stack is dead code; only encoded = in_seq@in_W+in_b is needed.
// Discrete decisions via f32-sigmoid emulation of numpy (saturation!).

__device__ __forceinline__ float gelu_f32(float x) {
    return 0.5f * x * (1.0f + erff(x * 0.70710678118654752440f));
}

__device__ __forceinline__ float sig32(float x) {
    return 1.0f / (1.0f + expf(-x));
}

// sc0 data loads (fast path only; read once, after the flag barrier).
__device__ __forceinline__ void load3_l2(const float* p0, const float* p1,
                                         const float* p2,
                                         float& v0, float& v1, float& v2) {
    asm volatile(
        "global_load_dword %0, %3, off sc0\n\t"
        "global_load_dword %1, %4, off sc0\n\t"
        "global_load_dword %2, %5, off sc0\n\t"
        "s_waitcnt vmcnt(0)"
        : "=&v"(v0), "=&v"(v1), "=&v"(v2)
        : "v"(p0), "v"(p1), "v"(p2)
        : "memory");
}
__device__ __forceinline__ float load1_l2(const float* p) {
    float v;
    asm volatile("global_load_dword %0, %1, off sc0\n\t"
                 "s_waitcnt vmcnt(0)"
                 : "=v"(v) : "v"(p) : "memory");
    return v;
}

// Group flag barrier: ONE lane (tid==0) atomically stores its own flag, then
// serially polls the 3 foreign flags. Agent-scope atomics bypass L1 (the
// R8/R9 stale-L1 spin is impossible) and are coherent across XCDs (G16).
__device__ __forceinline__ void flag_barrier(unsigned* flags, int b, int gbase,
                                             int mem, unsigned seq) {
    __hip_atomic_store(&flags[b], seq, __ATOMIC_RELAXED, __HIP_MEMORY_SCOPE_AGENT);
    #pragma unroll
    for (int j = 0; j < 4; ++j) {
        if (j == mem) continue;
        while (__hip_atomic_load(&flags[gbase + 8 * j],
                                 __ATOMIC_RELAXED, __HIP_MEMORY_SCOPE_AGENT) < seq)
            __builtin_amdgcn_s_sleep(1);
    }
}

// one 4-row x 4-col x 4-batch FMA chunk of the matvec
__device__ __forceinline__ void chunk_fma(float4 w0, float4 w1, float4 w2,
                                          float4 w3, const float4* g4p,
                                          int idx, float4 (&acc)[4]) {
    #pragma unroll
    for (int bi = 0; bi < 4; ++bi) {
        float4 gv = g4p[bi * 128 + idx];
        acc[bi].x = fmaf(gv.x,w0.x, fmaf(gv.y,w1.x, fmaf(gv.z,w2.x, fmaf(gv.w,w3.x, acc[bi].x))));
        acc[bi].y = fmaf(gv.x,w0.y, fmaf(gv.y,w1.y, fmaf(gv.z,w2.y, fmaf(gv.w,w3.y, acc[bi].y))));
        acc[bi].z = fmaf(gv.x,w0.z, fmaf(gv.y,w1.z, fmaf(gv.z,w2.z, fmaf(gv.w,w3.z, acc[bi].z))));
        acc[bi].w = fmaf(gv.x,w0.w, fmaf(gv.y,w1.w, fmaf(gv.z,w2.w, fmaf(gv.w,w3.w, acc[bi].w))));
    }
}

__global__ __launch_bounds__(NTHR, 2)
void s4_decode_kernel(
    const float* __restrict__ input_seq,   // (B,S,3)
    const float* __restrict__ in_W,        // (3,H)
    const float* __restrict__ in_b,        // (H)
    const float* __restrict__ Aarr,        // (L,H,N)
    const float* __restrict__ Barr,        // (L,H,N)
    const float* __restrict__ Carr,        // (L,H,N)
    const float* __restrict__ Darr,        // (L,H)
    const float* __restrict__ outW,        // (L,H,H)
    const float* __restrict__ outb,        // (L,H)
    const float* __restrict__ ln_g,        // (L,H)
    const float* __restrict__ ln_b,        // (L,H)
    const float* __restrict__ headW,       // (H,9)
    const float* __restrict__ headb,       // (9)
    float* __restrict__ out,               // (B,T,9)
    float* gws, float* zws,                // mailboxes: (256,512) each
    unsigned* fg, unsigned* fz,            // flags: (256) each, zeroed/launch
    unsigned* fx, unsigned* xid)           // XCD handshake, zeroed/launch
{
    __shared__ float4 ld_gall4[4 * 128];   // g for 4 group batches (f4 view)
    __shared__ float4 ld_z4[16 * 4 * 32];  // 32 KB matvec partials
    __shared__ float  ld_xd[HDIM];
    __shared__ float  ld_D0[HDIM];
    __shared__ float  ld_D1[HDIM];
    __shared__ float  ld_red[16];          // LN (v1,v2) per wave
    __shared__ float  ld_hred[8 * ODIM];   // head partials
    __shared__ float  ld_logit[ODIM + 1];
    __shared__ float  ld_dec[4];
    __shared__ int    ld_ptr;
    __shared__ int    ld_fast;
    float* ld_gall = (float*)ld_gall4;

    const int b    = blockIdx.x;
    const int tid  = threadIdx.x;
    const int hg   = tid >> 4;             // [0,32) for state phase
    const int n    = tid & 15;
    const int mem  = (b >> 3) & 3;         // slot in 4-WG group
    const int gbase = b - 8 * mem;         // group batches: gbase + 8j
    const int c4   = tid & 31;
    const int rg   = tid >> 5;             // [0,16)
    const int rgE  = (rg + ((b * 5) & 15)) & 15;  // per-WG row rotation
    const int base_row = rgE * 32;
    const int gb4  = base_row >> 2;        // float4 index of row window
    const int j0 = 0 + (0 >= mem), j1 = 1 + (1 >= mem), j2 = 2 + (2 >= mem);

    // ---- XCD-id handshake: data fast path only if all 4 members co-XCD ----
    unsigned myxcd;
    asm volatile("s_getreg_b32 %0, hwreg(HW_REG_XCC_ID)" : "=s"(myxcd));
    if (tid == 0) {
        __hip_atomic_store(&xid[b], myxcd, __ATOMIC_RELAXED, __HIP_MEMORY_SCOPE_AGENT);
        __hip_atomic_store(&fx[b], 1u, __ATOMIC_RELEASE, __HIP_MEMORY_SCOPE_AGENT);
        unsigned ok = 1;
        #pragma unroll
        for (int j = 0; j < 4; ++j) {
            if (j == mem) continue;
            while (__hip_atomic_load(&fx[gbase + 8 * j],
                                     __ATOMIC_ACQUIRE, __HIP_MEMORY_SCOPE_AGENT) == 0)
                __builtin_amdgcn_s_sleep(1);
            ok &= (__hip_atomic_load(&xid[gbase + 8 * j],
                                     __ATOMIC_RELAXED, __HIP_MEMORY_SCOPE_AGENT) == myxcd);
        }
        ld_fast = (int)ok;
    }

    // ---- persistent per-thread registers: states + SSM params ----
    float s0[16], s1[16];
    float A0[16], B0[16], C0[16], A1[16], B1[16], C1[16];
    #pragma unroll
    for (int k = 0; k < 16; ++k) {
        int h  = hg + 32 * k;
        int i0 = h * NDIM + n;
        int i1 = (HDIM + h) * NDIM + n;
        A0[k] = Aarr[i0]; B0[k] = Barr[i0]; C0[k] = Carr[i0];
        A1[k] = Aarr[i1]; B1[k] = Barr[i1]; C1[k] = Carr[i1];
        s0[k] = 0.f; s1[k] = 0.f;
    }

    // per-column constants
    const float inb_t = in_b[tid];
    const float w0 = in_W[tid], w1 = in_W[HDIM + tid], w2 = in_W[2 * HDIM + tid];
    const float ob0 = outb[tid], ob1 = outb[HDIM + tid];
    const float lg0 = ln_g[tid], lg1 = ln_g[HDIM + tid];
    const float lb0 = ln_b[tid], lb1 = ln_b[HDIM + tid];

    ld_D0[tid] = Darr[tid];
    ld_D1[tid] = Darr[HDIM + tid];

    const float4* Wsl = (const float4*)outW + mem * 32 + c4;

    float ctxr = 0.f;
    if (tid == 0) { ld_dec[0] = 0.f; ld_dec[1] = 0.f; ld_dec[2] = 1.f; }
    __syncthreads();
    const bool fast = (ld_fast != 0);      // block-uniform

    // prefetch first matvec's rows base_row..base_row+7
    float4 pw[8];
    #pragma unroll
    for (int j = 0; j < 8; ++j) pw[j] = Wsl[(size_t)(base_row + j) * 128];

    for (int i = 0; i < TSTEPS; ++i) {
        // ---- decoder input projection (ld_dec/ld_xd distinct: no hazard) ----
        float dpv = fmaf(ld_dec[0], w0, fmaf(ld_dec[1], w1, fmaf(ld_dec[2], w2, inb_t)));
        ld_xd[tid] = dpv;
        __syncthreads();

        #pragma unroll 1
        for (int blk = 0; blk < 2; ++blk) {
            const unsigned seq = (unsigned)(2 * i + blk + 1);
            // ---- S4 state update + gelu -> LDS slot + direct global publish ----
            {
                float* s  = blk ? s1 : s0;
                float* Ar = blk ? A1 : A0;
                float* Br = blk ? B1 : B0;
                float* Cr = blk ? C1 : C0;
                const float* Dl = blk ? ld_D1 : ld_D0;
                #pragma unroll
                for (int k = 0; k < 16; ++k) {
                    int h = hg + 32 * k;
                    float xh = ld_xd[h];
                    float sv = fmaf(Ar[k], s[k], Br[k] * xh);
                    s[k] = sv;
                    float p = sv * Cr[k];
                    p += __shfl_xor(p, 1);
                    p += __shfl_xor(p, 2);
                    p += __shfl_xor(p, 4);
                    p += __shfl_xor(p, 8);
                    if (n == 0) {
                        float gv = gelu_f32(p + Dl[h] * xh);
                        ld_gall[mem * HDIM + h] = gv;
                        if (fast) gws[b * HDIM + h] = gv;
                        else __hip_atomic_store(&gws[b * HDIM + h], gv,
                                 __ATOMIC_RELAXED, __HIP_MEMORY_SCOPE_AGENT);
                    }
                }
            }
            __syncthreads();               // drains g stores (vmcnt0)
            if (tid == 0) flag_barrier(fg, b, gbase, mem, seq);
            __syncthreads();
            // ---- fetch the 3 foreign g vectors (once, post-barrier) ----
            if (fast) {
                float v0, v1, v2;
                load3_l2(&gws[(gbase + 8 * j0) * HDIM + tid],
                         &gws[(gbase + 8 * j1) * HDIM + tid],
                         &gws[(gbase + 8 * j2) * HDIM + tid], v0, v1, v2);
                ld_gall[j0 * HDIM + tid] = v0;
                ld_gall[j1 * HDIM + tid] = v1;
                ld_gall[j2 * HDIM + tid] = v2;
            } else {
                ld_gall[j0 * HDIM + tid] =
                    __hip_atomic_load(&gws[(gbase + 8 * j0) * HDIM + tid],
                                      __ATOMIC_RELAXED, __HIP_MEMORY_SCOPE_AGENT);
                ld_gall[j1 * HDIM + tid] =
                    __hip_atomic_load(&gws[(gbase + 8 * j1) * HDIM + tid],
                                      __ATOMIC_RELAXED, __HIP_MEMORY_SCOPE_AGENT);
                ld_gall[j2 * HDIM + tid] =
                    __hip_atomic_load(&gws[(gbase + 8 * j2) * HDIM + tid],
                                      __ATOMIC_RELAXED, __HIP_MEMORY_SCOPE_AGENT);
            }
            __syncthreads();
            // ---- matvec: pw rows 0..7 prefetched, rows 8..31 streamed ----
            {
                const float4* Wb = Wsl + (size_t)blk * HDIM * 128;
                float4 sA[4], sB[4];
                #pragma unroll
                for (int j = 0; j < 4; ++j) sA[j] = Wb[(size_t)(base_row + 8 + j) * 128];
                #pragma unroll
                for (int j = 0; j < 4; ++j) sB[j] = Wb[(size_t)(base_row + 12 + j) * 128];
                float4 acc[4];
                #pragma unroll
                for (int bi = 0; bi < 4; ++bi) acc[bi] = make_float4(0.f,0.f,0.f,0.f);
                const float4* g4p = ld_gall4;
                chunk_fma(pw[0], pw[1], pw[2], pw[3], g4p, gb4 + 0, acc);
                chunk_fma(pw[4], pw[5], pw[6], pw[7], g4p, gb4 + 1, acc);
                chunk_fma(sA[0], sA[1], sA[2], sA[3], g4p, gb4 + 2, acc);
                #pragma unroll
                for (int j = 0; j < 4; ++j) sA[j] = Wb[(size_t)(base_row + 16 + j) * 128];
                chunk_fma(sB[0], sB[1], sB[2], sB[3], g4p, gb4 + 3, acc);
                #pragma unroll
                for (int j = 0; j < 4; ++j) sB[j] = Wb[(size_t)(base_row + 20 + j) * 128];
                chunk_fma(sA[0], sA[1], sA[2], sA[3], g4p, gb4 + 4, acc);
                #pragma unroll
                for (int j = 0; j < 4; ++j) sA[j] = Wb[(size_t)(base_row + 24 + j) * 128];
                chunk_fma(sB[0], sB[1], sB[2], sB[3], g4p, gb4 + 5, acc);
                #pragma unroll
                for (int j = 0; j < 4; ++j) sB[j] = Wb[(size_t)(base_row + 28 + j) * 128];
                chunk_fma(sA[0], sA[1], sA[2], sA[3], g4p, gb4 + 6, acc);
                chunk_fma(sB[0], sB[1], sB[2], sB[3], g4p, gb4 + 7, acc);
                #pragma unroll
                for (int bi = 0; bi < 4; ++bi)
                    ld_z4[(rg * 4 + bi) * 32 + c4] = acc[bi];
            }
            __syncthreads();
            // ---- reduce 16 row-group partials, ship slices to owners ----
            {
                const float* zf = (const float*)ld_z4;
                int bi2 = tid >> 7;        // group member index
                int col = tid & 127;
                float zv = 0.f;
                #pragma unroll
                for (int k = 0; k < 16; ++k) zv += zf[(k * 4 + bi2) * 128 + col];
                float* zp = &zws[(gbase + 8 * bi2) * HDIM + mem * 128 + col];
                if (fast) *zp = zv;
                else __hip_atomic_store(zp, zv, __ATOMIC_RELAXED, __HIP_MEMORY_SCOPE_AGENT);
            }
            __syncthreads();               // drains z stores
            // prefetch NEXT matvec's first 8 rows; fill overlaps the z-wait
            {
                const float4* Wn = (blk == 0) ? (Wsl + (size_t)HDIM * 128) : Wsl;
                #pragma unroll
                for (int j = 0; j < 8; ++j) pw[j] = Wn[(size_t)(base_row + j) * 128];
            }
            if (tid == 0) flag_barrier(fz, b, gbase, mem, seq);
            __syncthreads();
            // ---- read own full z, residual + one-pass LN ----
            {
                float zraw = fast ? load1_l2(&zws[b * HDIM + tid])
                                  : __hip_atomic_load(&zws[b * HDIM + tid],
                                                      __ATOMIC_RELAXED,
                                                      __HIP_MEMORY_SCOPE_AGENT);
                float z = zraw + (blk ? ob1 : ob0);
                float res = (i == 0) ? dpv : z;    // ref: residual=proj @ i==0
                float tmp = z + res;
                float v1 = tmp, v2 = tmp * tmp;
                #pragma unroll
                for (int m = 1; m < 64; m <<= 1) {
                    v1 += __shfl_xor(v1, m);
                    v2 += __shfl_xor(v2, m);
                }
                if ((tid & 63) == 0) {
                    ld_red[2 * (tid >> 6)]     = v1;
                    ld_red[2 * (tid >> 6) + 1] = v2;
                }
                __syncthreads();
                float s1r = 0.f, s2r = 0.f;
                #pragma unroll
                for (int q = 0; q < 8; ++q) { s1r += ld_red[2*q]; s2r += ld_red[2*q+1]; }
                float mu  = s1r * (1.f / 512.f);
                float var = s2r * (1.f / 512.f) - mu * mu;
                float rs  = rsqrtf(var + 1e-5f);
                ld_xd[tid] = (tmp - mu) * rs * (blk ? lg1 : lg0) + (blk ? lb1 : lb0);
                __syncthreads();
            }
        }

        // ================= head #1 =================
        {
            float v = ld_xd[tid] + ctxr;
            const float* w = headW + tid * ODIM;
            float p[ODIM];
            #pragma unroll
            for (int o = 0; o < ODIM; ++o) p[o] = v * w[o];
            #pragma unroll
            for (int m = 1; m < 64; m <<= 1) {
                #pragma unroll
                for (int o = 0; o < ODIM; ++o) p[o] += __shfl_xor(p[o], m);
            }
            if ((tid & 63) == 0) {
                int wv = tid >> 6;
                #pragma unroll
                for (int o = 0; o < ODIM; ++o) ld_hred[wv * ODIM + o] = p[o];
            }
            __syncthreads();
            if (tid < ODIM) {
                float s = headb[tid];
                #pragma unroll
                for (int wv = 0; wv < 8; ++wv) s += ld_hred[wv * ODIM + tid];
                ld_logit[tid] = s;
            }
            __syncthreads();
        }

        const bool is_out = ((i & 1) == 0);
        if (is_out) {
            if (tid < ODIM)
                out[(b * TSTEPS + i) * ODIM + tid] = sig32(ld_logit[tid]);
            if (tid == 0) {
                float nc = (sig32(ld_logit[0]) > 0.5f) ? 1.f : 0.f;
                ld_dec[0] = nc; ld_dec[1] = 1.f; ld_dec[2] = 0.f;
            }
            __syncthreads();
        } else {
            // np.argmax over f32 SIGMOIDS (saturation => not logit-argmax!)
            if (tid == 0) {
                int best = 0; float bv = sig32(ld_logit[3]);
                #pragma unroll
                for (int o = 1; o < 6; ++o) {
                    float v2 = sig32(ld_logit[3 + o]);
                    if (v2 > bv) { bv = v2; best = o; }
                }
                ld_ptr = best;
                ld_dec[0] = 0.f; ld_dec[1] = 0.f; ld_dec[2] = 1.f;
            }
            __syncthreads();
            {   // ctx += encoded[b, ptr, :]
                const float* iseq = input_seq + (b * SEQ + ld_ptr) * 3;
                float e0 = iseq[0], e1 = iseq[1], e2 = iseq[2];
                ctxr += fmaf(e0, w0, fmaf(e1, w1, fmaf(e2, w2, inb_t)));
            }
            __syncthreads();
            // ================= head #2 =================
            {
                float v = ld_xd[tid] + ctxr;
                const float* w = headW + tid * ODIM;
                float p[ODIM];
                #pragma unroll
                for (int o = 0; o < ODIM; ++o) p[o] = v * w[o];
                #pragma unroll
                for (int m = 1; m < 64; m <<= 1) {
                    #pragma unroll
                    for (int o = 0; o < ODIM; ++o) p[o] += __shfl_xor(p[o], m);
                }
                if ((tid & 63) == 0) {
                    int wv = tid >> 6;
                    #pragma unroll
                    for (int o = 0; o < ODIM; ++o) ld_hred[wv * ODIM + o] = p[o];
                }
                __syncthreads();
                if (tid < ODIM) {
                    float s = headb[tid];
                    #pragma unroll
                    for (int wv = 0; wv < 8; ++wv) s += ld_hred[wv * ODIM + tid];
                    out[(b * TSTEPS + i) * ODIM + tid] = sig32(s);
                }
            }
            __syncthreads();
        }
    }
}

extern "C" void kernel_launch(void* const* d_in, const int* in_sizes, int n_in,
                              void* d_out, int out_size, void* d_ws, size_t ws_size,
                              hipStream_t stream) {
    (void)in_sizes; (void)n_in; (void)ws_size; (void)out_size;
    const float* input_seq = (const float*)d_in[0];
    // d_in[1] = autoregressive_steps (scalar) -- T fixed at 63 by the model
    const float* in_W   = (const float*)d_in[2];
    const float* in_b   = (const float*)d_in[3];
    const float* Aarr   = (const float*)d_in[4];
    const float* Barr   = (const float*)d_in[5];
    const float* Carr   = (const float*)d_in[6];
    const float* Darr   = (const float*)d_in[7];
    const float* outW   = (const float*)d_in[8];
    const float* outb   = (const float*)d_in[9];
    const float* ln_g   = (const float*)d_in[10];
    const float* ln_b   = (const float*)d_in[11];
    const float* headW  = (const float*)d_in[12];
    const float* headb  = (const float*)d_in[13];
    float* out = (float*)d_out;

    // ws layout: fg [0,1K), fz [1K,2K), fx [2K,3K), xid [3K,4K), gws, zws
    unsigned* fg  = (unsigned*)d_ws;
    unsigned* fz  = fg + BATCH;
    unsigned* fx  = fz + BATCH;
    unsigned* xid = fx + BATCH;
    float* gws = (float*)((char*)d_ws + 4096);
    float* zws = gws + BATCH * HDIM;

    // zero all flags every launch (ws is poisoned 0xAA by the harness)
    hipMemsetAsync(d_ws, 0, 4096, stream);

    s4_decode_kernel<<<BATCH, NTHR, 0, stream>>>(
        input_seq, in_W, in_b, Aarr, Barr, Carr, Darr,
        outW, outb, ln_g, ln_b, headW, headb, out,
        gws, zws, fg, fz, fx, xid);
}

// Round 11
// 2557.543 us; speedup vs baseline: 1.0113x; 1.0113x over previous
//
#include <hip/hip_runtime.h>
#include <math.h>

// Problem constants (fixed by the reference)
#define HDIM   512
#define NDIM   16
#define SEQ    64
#define TSTEPS 63
#define BATCH  256
#define ODIM   9
#define NTHR   512

// R11 = R10 with the VGPR cap lifted: __launch_bounds__(512, 1).
// R10 evidence: FETCH 2.5GB / WRITE 204MB / VALU 16% = scratch spill-reload
// (~310B/thread/step) — persistent s+A/B/C arrays (128 regs) + pw[8] exceed
// the 128-VGPR cap that (512,2) imposed. We run 256 WGs on 256 CUs -> always
// 1 block/CU -> 8 waves/CU -> 2 waves/SIMD, which the RF supports at 256
// VGPRs/thread (m69). (512,1) keeps that occupancy and doubles the budget.
// Flags: agent-scope atomics (L1-bypassing; R8/R9 sc0-poll stale-L1 hang).
// Data: R7-proven L2 fast path (plain store + one post-barrier sc0 load) for
// co-XCD groups, agent-atomic fallback otherwise (G16-safe).
//
// Encoder S4 stack is dead code; only encoded = in_seq@in_W+in_b is needed.
// Discrete decisions via f32-sigmoid emulation of numpy (saturation!).

__device__ __forceinline__ float gelu_f32(float x) {
    return 0.5f * x * (1.0f + erff(x * 0.70710678118654752440f));
}

__device__ __forceinline__ float sig32(float x) {
    return 1.0f / (1.0f + expf(-x));
}

// sc0 data loads (fast path only; read once, after the flag barrier).
__device__ __forceinline__ void load3_l2(const float* p0, const float* p1,
                                         const float* p2,
                                         float& v0, float& v1, float& v2) {
    asm volatile(
        "global_load_dword %0, %3, off sc0\n\t"
        "global_load_dword %1, %4, off sc0\n\t"
        "global_load_dword %2, %5, off sc0\n\t"
        "s_waitcnt vmcnt(0)"
        : "=&v"(v0), "=&v"(v1), "=&v"(v2)
        : "v"(p0), "v"(p1), "v"(p2)
        : "memory");
}
__device__ __forceinline__ float load1_l2(const float* p) {
    float v;
    asm volatile("global_load_dword %0, %1, off sc0\n\t"
                 "s_waitcnt vmcnt(0)"
                 : "=v"(v) : "v"(p) : "memory");
    return v;
}

// Group flag barrier: ONE lane (tid==0) atomically stores its own flag, then
// serially polls the 3 foreign flags. Agent-scope atomics bypass L1 (the
// R8/R9 stale-L1 spin is impossible) and are coherent across XCDs (G16).
__device__ __forceinline__ void flag_barrier(unsigned* flags, int b, int gbase,
                                             int mem, unsigned seq) {
    __hip_atomic_store(&flags[b], seq, __ATOMIC_RELAXED, __HIP_MEMORY_SCOPE_AGENT);
    #pragma unroll
    for (int j = 0; j < 4; ++j) {
        if (j == mem) continue;
        while (__hip_atomic_load(&flags[gbase + 8 * j],
                                 __ATOMIC_RELAXED, __HIP_MEMORY_SCOPE_AGENT) < seq)
            __builtin_amdgcn_s_sleep(1);
    }
}

// one 4-row x 4-col x 4-batch FMA chunk of the matvec
__device__ __forceinline__ void chunk_fma(float4 w0, float4 w1, float4 w2,
                                          float4 w3, const float4* g4p,
                                          int idx, float4 (&acc)[4]) {
    #pragma unroll
    for (int bi = 0; bi < 4; ++bi) {
        float4 gv = g4p[bi * 128 + idx];
        acc[bi].x = fmaf(gv.x,w0.x, fmaf(gv.y,w1.x, fmaf(gv.z,w2.x, fmaf(gv.w,w3.x, acc[bi].x))));
        acc[bi].y = fmaf(gv.x,w0.y, fmaf(gv.y,w1.y, fmaf(gv.z,w2.y, fmaf(gv.w,w3.y, acc[bi].y))));
        acc[bi].z = fmaf(gv.x,w0.z, fmaf(gv.y,w1.z, fmaf(gv.z,w2.z, fmaf(gv.w,w3.z, acc[bi].z))));
        acc[bi].w = fmaf(gv.x,w0.w, fmaf(gv.y,w1.w, fmaf(gv.z,w2.w, fmaf(gv.w,w3.w, acc[bi].w))));
    }
}

__global__ __launch_bounds__(NTHR, 1)   // 1 block/CU guaranteed by grid; 256-VGPR budget
void s4_decode_kernel(
    const float* __restrict__ input_seq,   // (B,S,3)
    const float* __restrict__ in_W,        // (3,H)
    const float* __restrict__ in_b,        // (H)
    const float* __restrict__ Aarr,        // (L,H,N)
    const float* __restrict__ Barr,        // (L,H,N)
    const float* __restrict__ Carr,        // (L,H,N)
    const float* __restrict__ Darr,        // (L,H)
    const float* __restrict__ outW,        // (L,H,H)
    const float* __restrict__ outb,        // (L,H)
    const float* __restrict__ ln_g,        // (L,H)
    const float* __restrict__ ln_b,        // (L,H)
    const float* __restrict__ headW,       // (H,9)
    const float* __restrict__ headb,       // (9)
    float* __restrict__ out,               // (B,T,9)
    float* gws, float* zws,                // mailboxes: (256,512) each
    unsigned* fg, unsigned* fz,            // flags: (256) each, zeroed/launch
    unsigned* fx, unsigned* xid)           // XCD handshake, zeroed/launch
{
    __shared__ float4 ld_gall4[4 * 128];   // g for 4 group batches (f4 view)
    __shared__ float4 ld_z4[16 * 4 * 32];  // 32 KB matvec partials
    __shared__ float  ld_xd[HDIM];
    __shared__ float  ld_D0[HDIM];
    __shared__ float  ld_D1[HDIM];
    __shared__ float  ld_red[16];          // LN (v1,v2) per wave
    __shared__ float  ld_hred[8 * ODIM];   // head partials
    __shared__ float  ld_logit[ODIM + 1];
    __shared__ float  ld_dec[4];
    __shared__ int    ld_ptr;
    __shared__ int    ld_fast;
    float* ld_gall = (float*)ld_gall4;

    const int b    = blockIdx.x;
    const int tid  = threadIdx.x;
    const int hg   = tid >> 4;             // [0,32) for state phase
    const int n    = tid & 15;
    const int mem  = (b >> 3) & 3;         // slot in 4-WG group
    const int gbase = b - 8 * mem;         // group batches: gbase + 8j
    const int c4   = tid & 31;
    const int rg   = tid >> 5;             // [0,16)
    const int rgE  = (rg + ((b * 5) & 15)) & 15;  // per-WG row rotation
    const int base_row = rgE * 32;
    const int gb4  = base_row >> 2;        // float4 index of row window
    const int j0 = 0 + (0 >= mem), j1 = 1 + (1 >= mem), j2 = 2 + (2 >= mem);

    // ---- XCD-id handshake: data fast path only if all 4 members co-XCD ----
    unsigned myxcd;
    asm volatile("s_getreg_b32 %0, hwreg(HW_REG_XCC_ID)" : "=s"(myxcd));
    if (tid == 0) {
        __hip_atomic_store(&xid[b], myxcd, __ATOMIC_RELAXED, __HIP_MEMORY_SCOPE_AGENT);
        __hip_atomic_store(&fx[b], 1u, __ATOMIC_RELEASE, __HIP_MEMORY_SCOPE_AGENT);
        unsigned ok = 1;
        #pragma unroll
        for (int j = 0; j < 4; ++j) {
            if (j == mem) continue;
            while (__hip_atomic_load(&fx[gbase + 8 * j],
                                     __ATOMIC_ACQUIRE, __HIP_MEMORY_SCOPE_AGENT) == 0)
                __builtin_amdgcn_s_sleep(1);
            ok &= (__hip_atomic_load(&xid[gbase + 8 * j],
                                     __ATOMIC_RELAXED, __HIP_MEMORY_SCOPE_AGENT) == myxcd);
        }
        ld_fast = (int)ok;
    }

    // ---- persistent per-thread registers: states + SSM params ----
    float s0[16], s1[16];
    float A0[16], B0[16], C0[16], A1[16], B1[16], C1[16];
    #pragma unroll
    for (int k = 0; k < 16; ++k) {
        int h  = hg + 32 * k;
        int i0 = h * NDIM + n;
        int i1 = (HDIM + h) * NDIM + n;
        A0[k] = Aarr[i0]; B0[k] = Barr[i0]; C0[k] = Carr[i0];
        A1[k] = Aarr[i1]; B1[k] = Barr[i1]; C1[k] = Carr[i1];
        s0[k] = 0.f; s1[k] = 0.f;
    }

    // per-column constants
    const float inb_t = in_b[tid];
    const float w0 = in_W[tid], w1 = in_W[HDIM + tid], w2 = in_W[2 * HDIM + tid];
    const float ob0 = outb[tid], ob1 = outb[HDIM + tid];
    const float lg0 = ln_g[tid], lg1 = ln_g[HDIM + tid];
    const float lb0 = ln_b[tid], lb1 = ln_b[HDIM + tid];

    ld_D0[tid] = Darr[tid];
    ld_D1[tid] = Darr[HDIM + tid];

    const float4* Wsl = (const float4*)outW + mem * 32 + c4;

    float ctxr = 0.f;
    if (tid == 0) { ld_dec[0] = 0.f; ld_dec[1] = 0.f; ld_dec[2] = 1.f; }
    __syncthreads();
    const bool fast = (ld_fast != 0);      // block-uniform

    // prefetch first matvec's rows base_row..base_row+7
    float4 pw[8];
    #pragma unroll
    for (int j = 0; j < 8; ++j) pw[j] = Wsl[(size_t)(base_row + j) * 128];

    for (int i = 0; i < TSTEPS; ++i) {
        // ---- decoder input projection (ld_dec/ld_xd distinct: no hazard) ----
        float dpv = fmaf(ld_dec[0], w0, fmaf(ld_dec[1], w1, fmaf(ld_dec[2], w2, inb_t)));
        ld_xd[tid] = dpv;
        __syncthreads();

        #pragma unroll 1
        for (int blk = 0; blk < 2; ++blk) {
            const unsigned seq = (unsigned)(2 * i + blk + 1);
            // ---- S4 state update + gelu -> LDS slot + direct global publish ----
            {
                float* s  = blk ? s1 : s0;
                float* Ar = blk ? A1 : A0;
                float* Br = blk ? B1 : B0;
                float* Cr = blk ? C1 : C0;
                const float* Dl = blk ? ld_D1 : ld_D0;
                #pragma unroll
                for (int k = 0; k < 16; ++k) {
                    int h = hg + 32 * k;
                    float xh = ld_xd[h];
                    float sv = fmaf(Ar[k], s[k], Br[k] * xh);
                    s[k] = sv;
                    float p = sv * Cr[k];
                    p += __shfl_xor(p, 1);
                    p += __shfl_xor(p, 2);
                    p += __shfl_xor(p, 4);
                    p += __shfl_xor(p, 8);
                    if (n == 0) {
                        float gv = gelu_f32(p + Dl[h] * xh);
                        ld_gall[mem * HDIM + h] = gv;
                        if (fast) gws[b * HDIM + h] = gv;
                        else __hip_atomic_store(&gws[b * HDIM + h], gv,
                                 __ATOMIC_RELAXED, __HIP_MEMORY_SCOPE_AGENT);
                    }
                }
            }
            __syncthreads();               // drains g stores (vmcnt0)
            if (tid == 0) flag_barrier(fg, b, gbase, mem, seq);
            __syncthreads();
            // ---- fetch the 3 foreign g vectors (once, post-barrier) ----
            if (fast) {
                float v0, v1, v2;
                load3_l2(&gws[(gbase + 8 * j0) * HDIM + tid],
                         &gws[(gbase + 8 * j1) * HDIM + tid],
                         &gws[(gbase + 8 * j2) * HDIM + tid], v0, v1, v2);
                ld_gall[j0 * HDIM + tid] = v0;
                ld_gall[j1 * HDIM + tid] = v1;
                ld_gall[j2 * HDIM + tid] = v2;
            } else {
                ld_gall[j0 * HDIM + tid] =
                    __hip_atomic_load(&gws[(gbase + 8 * j0) * HDIM + tid],
                                      __ATOMIC_RELAXED, __HIP_MEMORY_SCOPE_AGENT);
                ld_gall[j1 * HDIM + tid] =
                    __hip_atomic_load(&gws[(gbase + 8 * j1) * HDIM + tid],
                                      __ATOMIC_RELAXED, __HIP_MEMORY_SCOPE_AGENT);
                ld_gall[j2 * HDIM + tid] =
                    __hip_atomic_load(&gws[(gbase + 8 * j2) * HDIM + tid],
                                      __ATOMIC_RELAXED, __HIP_MEMORY_SCOPE_AGENT);
            }
            __syncthreads();
            // ---- matvec: pw rows 0..7 prefetched, rows 8..31 streamed ----
            {
                const float4* Wb = Wsl + (size_t)blk * HDIM * 128;
                float4 sA[4], sB[4];
                #pragma unroll
                for (int j = 0; j < 4; ++j) sA[j] = Wb[(size_t)(base_row + 8 + j) * 128];
                #pragma unroll
                for (int j = 0; j < 4; ++j) sB[j] = Wb[(size_t)(base_row + 12 + j) * 128];
                float4 acc[4];
                #pragma unroll
                for (int bi = 0; bi < 4; ++bi) acc[bi] = make_float4(0.f,0.f,0.f,0.f);
                const float4* g4p = ld_gall4;
                chunk_fma(pw[0], pw[1], pw[2], pw[3], g4p, gb4 + 0, acc);
                chunk_fma(pw[4], pw[5], pw[6], pw[7], g4p, gb4 + 1, acc);
                chunk_fma(sA[0], sA[1], sA[2], sA[3], g4p, gb4 + 2, acc);
                #pragma unroll
                for (int j = 0; j < 4; ++j) sA[j] = Wb[(size_t)(base_row + 16 + j) * 128];
                chunk_fma(sB[0], sB[1], sB[2], sB[3], g4p, gb4 + 3, acc);
                #pragma unroll
                for (int j = 0; j < 4; ++j) sB[j] = Wb[(size_t)(base_row + 20 + j) * 128];
                chunk_fma(sA[0], sA[1], sA[2], sA[3], g4p, gb4 + 4, acc);
                #pragma unroll
                for (int j = 0; j < 4; ++j) sA[j] = Wb[(size_t)(base_row + 24 + j) * 128];
                chunk_fma(sB[0], sB[1], sB[2], sB[3], g4p, gb4 + 5, acc);
                #pragma unroll
                for (int j = 0; j < 4; ++j) sB[j] = Wb[(size_t)(base_row + 28 + j) * 128];
                chunk_fma(sA[0], sA[1], sA[2], sA[3], g4p, gb4 + 6, acc);
                chunk_fma(sB[0], sB[1], sB[2], sB[3], g4p, gb4 + 7, acc);
                #pragma unroll
                for (int bi = 0; bi < 4; ++bi)
                    ld_z4[(rg * 4 + bi) * 32 + c4] = acc[bi];
            }
            __syncthreads();
            // ---- reduce 16 row-group partials, ship slices to owners ----
            {
                const float* zf = (const float*)ld_z4;
                int bi2 = tid >> 7;        // group member index
                int col = tid & 127;
                float zv = 0.f;
                #pragma unroll
                for (int k = 0; k < 16; ++k) zv += zf[(k * 4 + bi2) * 128 + col];
                float* zp = &zws[(gbase + 8 * bi2) * HDIM + mem * 128 + col];
                if (fast) *zp = zv;
                else __hip_atomic_store(zp, zv, __ATOMIC_RELAXED, __HIP_MEMORY_SCOPE_AGENT);
            }
            __syncthreads();               // drains z stores
            // prefetch NEXT matvec's first 8 rows; fill overlaps the z-wait
            {
                const float4* Wn = (blk == 0) ? (Wsl + (size_t)HDIM * 128) : Wsl;
                #pragma unroll
                for (int j = 0; j < 8; ++j) pw[j] = Wn[(size_t)(base_row + j) * 128];
            }
            if (tid == 0) flag_barrier(fz, b, gbase, mem, seq);
            __syncthreads();
            // ---- read own full z, residual + one-pass LN ----
            {
                float zraw = fast ? load1_l2(&zws[b * HDIM + tid])
                                  : __hip_atomic_load(&zws[b * HDIM + tid],
                                                      __ATOMIC_RELAXED,
                                                      __HIP_MEMORY_SCOPE_AGENT);
                float z = zraw + (blk ? ob1 : ob0);
                float res = (i == 0) ? dpv : z;    // ref: residual=proj @ i==0
                float tmp = z + res;
                float v1 = tmp, v2 = tmp * tmp;
                #pragma unroll
                for (int m = 1; m < 64; m <<= 1) {
                    v1 += __shfl_xor(v1, m);
                    v2 += __shfl_xor(v2, m);
                }
                if ((tid & 63) == 0) {
                    ld_red[2 * (tid >> 6)]     = v1;
                    ld_red[2 * (tid >> 6) + 1] = v2;
                }
                __syncthreads();
                float s1r = 0.f, s2r = 0.f;
                #pragma unroll
                for (int q = 0; q < 8; ++q) { s1r += ld_red[2*q]; s2r += ld_red[2*q+1]; }
                float mu  = s1r * (1.f / 512.f);
                float var = s2r * (1.f / 512.f) - mu * mu;
                float rs  = rsqrtf(var + 1e-5f);
                ld_xd[tid] = (tmp - mu) * rs * (blk ? lg1 : lg0) + (blk ? lb1 : lb0);
                __syncthreads();
            }
        }

        // ================= head #1 =================
        {
            float v = ld_xd[tid] + ctxr;
            const float* w = headW + tid * ODIM;
            float p[ODIM];
            #pragma unroll
            for (int o = 0; o < ODIM; ++o) p[o] = v * w[o];
            #pragma unroll
            for (int m = 1; m < 64; m <<= 1) {
                #pragma unroll
                for (int o = 0; o < ODIM; ++o) p[o] += __shfl_xor(p[o], m);
            }
            if ((tid & 63) == 0) {
                int wv = tid >> 6;
                #pragma unroll
                for (int o = 0; o < ODIM; ++o) ld_hred[wv * ODIM + o] = p[o];
            }
            __syncthreads();
            if (tid < ODIM) {
                float s = headb[tid];
                #pragma unroll
                for (int wv = 0; wv < 8; ++wv) s += ld_hred[wv * ODIM + tid];
                ld_logit[tid] = s;
            }
            __syncthreads();
        }

        const bool is_out = ((i & 1) == 0);
        if (is_out) {
            if (tid < ODIM)
                out[(b * TSTEPS + i) * ODIM + tid] = sig32(ld_logit[tid]);
            if (tid == 0) {
                float nc = (sig32(ld_logit[0]) > 0.5f) ? 1.f : 0.f;
                ld_dec[0] = nc; ld_dec[1] = 1.f; ld_dec[2] = 0.f;
            }
            __syncthreads();
        } else {
            // np.argmax over f32 SIGMOIDS (saturation => not logit-argmax!)
            if (tid == 0) {
                int best = 0; float bv = sig32(ld_logit[3]);
                #pragma unroll
                for (int o = 1; o < 6; ++o) {
                    float v2 = sig32(ld_logit[3 + o]);
                    if (v2 > bv) { bv = v2; best = o; }
                }
                ld_ptr = best;
                ld_dec[0] = 0.f; ld_dec[1] = 0.f; ld_dec[2] = 1.f;
            }
            __syncthreads();
            {   // ctx += encoded[b, ptr, :]
                const float* iseq = input_seq + (b * SEQ + ld_ptr) * 3;
                float e0 = iseq[0], e1 = iseq[1], e2 = iseq[2];
                ctxr += fmaf(e0, w0, fmaf(e1, w1, fmaf(e2, w2, inb_t)));
            }
            __syncthreads();
            // ================= head #2 =================
            {
                float v = ld_xd[tid] + ctxr;
                const float* w = headW + tid * ODIM;
                float p[ODIM];
                #pragma unroll
                for (int o = 0; o < ODIM; ++o) p[o] = v * w[o];
                #pragma unroll
                for (int m = 1; m < 64; m <<= 1) {
                    #pragma unroll
                    for (int o = 0; o < ODIM; ++o) p[o] += __shfl_xor(p[o], m);
                }
                if ((tid & 63) == 0) {
                    int wv = tid >> 6;
                    #pragma unroll
                    for (int o = 0; o < ODIM; ++o) ld_hred[wv * ODIM + o] = p[o];
                }
                __syncthreads();
                if (tid < ODIM) {
                    float s = headb[tid];
                    #pragma unroll
                    for (int wv = 0; wv < 8; ++wv) s += ld_hred[wv * ODIM + tid];
                    out[(b * TSTEPS + i) * ODIM + tid] = sig32(s);
                }
            }
            __syncthreads();
        }
    }
}

extern "C" void kernel_launch(void* const* d_in, const int* in_sizes, int n_in,
                              void* d_out, int out_size, void* d_ws, size_t ws_size,
                              hipStream_t stream) {
    (void)in_sizes; (void)n_in; (void)ws_size; (void)out_size;
    const float* input_seq = (const float*)d_in[0];
    // d_in[1] = autoregressive_steps (scalar) -- T fixed at 63 by the model
    const float* in_W   = (const float*)d_in[2];
    const float* in_b   = (const float*)d_in[3];
    const float* Aarr   = (const float*)d_in[4];
    const float* Barr   = (const float*)d_in[5];
    const float* Carr   = (const float*)d_in[6];
    const float* Darr   = (const float*)d_in[7];
    const float* outW   = (const float*)d_in[8];
    const float* outb   = (const float*)d_in[9];
    const float* ln_g   = (const float*)d_in[10];
    const float* ln_b   = (const float*)d_in[11];
    const float* headW  = (const float*)d_in[12];
    const float* headb  = (const float*)d_in[13];
    float* out = (float*)d_out;

    // ws layout: fg [0,1K), fz [1K,2K), fx [2K,3K), xid [3K,4K), gws, zws
    unsigned* fg  = (unsigned*)d_ws;
    unsigned* fz  = fg + BATCH;
    unsigned* fx  = fz + BATCH;
    unsigned* xid = fx + BATCH;
    float* gws = (float*)((char*)d_ws + 4096);
    float* zws = gws + BATCH * HDIM;

    // zero all flags every launch (ws is poisoned 0xAA by the harness)
    hipMemsetAsync(d_ws, 0, 4096, stream);

    s4_decode_kernel<<<BATCH, NTHR, 0, stream>>>(
        input_seq, in_W, in_b, Aarr, Barr, Carr, Darr,
        outW, outb, ln_g, ln_b, headW, headb, out,
        gws, zws, fg, fz, fx, xid);
}

// Round 12
// 2491.507 us; speedup vs baseline: 1.0381x; 1.0265x over previous
//
#include <hip/hip_runtime.h>
#include <math.h>

// Problem constants (fixed by the reference)
#define HDIM   512
#define NDIM   16
#define SEQ    64
#define TSTEPS 63
#define BATCH  256
#define ODIM   9
#define NTHR   1024
#define NWG    (BATCH / 2)   // 2 batches per workgroup

// R12: batch-pair workgroups, zero inter-WG communication.
// R7's cross-WG scheme pays ~11.6us/step in flag-round latency for a 1MB/step
// fill; R10/R11 showed its register headroom is gone (compiler caps at 128
// VGPRs regardless of launch_bounds and spills -> 2.5GB HBM reload).
// This design: 128 WGs x 1024 thr, each WG owns batches {2bx, 2bx+1}. One
// weight stream feeds BOTH batches (2 FMAs per float4 load -> 2x intensity
// vs R4's single-batch 1840us), every exchange is a __syncthreads, no flags,
// no mailboxes, no XCD assumptions. Fill floor: 2MB/step/CU ~ 13.3us/step.
// Register plan: states 32 + shared A/B/C 48 + ~14 consts, matvec kept lean
// (no ping-pong buffers; ob/lg/lb read from global in the LN phase).
// amdgpu_waves_per_eu(4,4): 1024 thr = exactly 4 waves/EU; pin it so the
// compiler targets the full 128-VGPR budget (R5: (1024,1) -> it chose 64).
//
// Encoder S4 stack is dead code; only encoded = in_seq@in_W+in_b is needed.
// Discrete decisions via f32-sigmoid emulation of numpy (saturation!).

__device__ __forceinline__ float gelu_f32(float x) {
    return 0.5f * x * (1.0f + erff(x * 0.70710678118654752440f));
}

__device__ __forceinline__ float sig32(float x) {
    return 1.0f / (1.0f + expf(-x));
}

__global__ void __launch_bounds__(NTHR)
__attribute__((amdgpu_waves_per_eu(4, 4)))
s4_decode_kernel(
    const float* __restrict__ input_seq,   // (B,S,3)
    const float* __restrict__ in_W,        // (3,H)
    const float* __restrict__ in_b,        // (H)
    const float* __restrict__ Aarr,        // (L,H,N)
    const float* __restrict__ Barr,        // (L,H,N)
    const float* __restrict__ Carr,        // (L,H,N)
    const float* __restrict__ Darr,        // (L,H)
    const float* __restrict__ outW,        // (L,H,H)
    const float* __restrict__ outb,        // (L,H)
    const float* __restrict__ ln_g,        // (L,H)
    const float* __restrict__ ln_b,        // (L,H)
    const float* __restrict__ headW,       // (H,9)
    const float* __restrict__ headb,       // (9)
    float* __restrict__ out)               // (B,T,9)
{
    __shared__ float ld_xd[2 * HDIM];      // xd for both batches
    __shared__ float ld_g0[HDIM];          // gelu output, batch 0
    __shared__ float ld_g1[HDIM];          // gelu output, batch 1
    __shared__ float ld_z[2 * 8 * HDIM];   // matvec partials (32 KB)
    __shared__ float ld_D[2 * HDIM];
    __shared__ float ld_red[32];           // LN (v1,v2) per wave
    __shared__ float ld_hred[16 * ODIM];   // head partials per wave
    __shared__ float ld_logit[2][12];
    __shared__ float ld_dec[2][4];
    __shared__ int   ld_ptr[2];

    const int bx   = blockIdx.x;
    const int b0   = 2 * bx;               // this WG's batches: b0, b0+1
    const int tid  = threadIdx.x;
    const int hg   = tid >> 4;             // [0,64)  state-phase h group
    const int n    = tid & 15;             // state-phase n
    const int half = tid >> 9;             // 0/1 = batch slot for col phases
    const int col  = tid & 511;            // column index for col phases
    const int hq   = tid >> 7;             // [0,8)   matvec 64-row window
    const int cq   = tid & 127;            // matvec float4 column
    // distinct row-phase per same-XCD WG (bx>>3 is distinct there); gcd(5,32)=1
    const int rotp = ((bx >> 3) * 5) & 31;

    // ---- persistent registers: states (per batch) + A/B/C (shared) ----
    float sA0[8], sA1[8], sB0[8], sB1[8];  // s[layer 0/1][batch 0/1]
    float A0[8], B0[8], C0[8], A1[8], B1[8], C1[8];
    #pragma unroll
    for (int k = 0; k < 8; ++k) {
        int i0 = tid + 1024 * k;           // = h*16+n for h=hg+64k
        int i1 = 8192 + i0;
        A0[k] = Aarr[i0]; B0[k] = Barr[i0]; C0[k] = Carr[i0];
        A1[k] = Aarr[i1]; B1[k] = Barr[i1]; C1[k] = Carr[i1];
        sA0[k] = 0.f; sA1[k] = 0.f; sB0[k] = 0.f; sB1[k] = 0.f;
    }

    // per-column constants kept in regs (used every step)
    const float inb_t = in_b[col];
    const float w0 = in_W[col], w1 = in_W[HDIM + col], w2 = in_W[2 * HDIM + col];

    if (tid < HDIM) { ld_D[tid] = Darr[tid]; ld_D[HDIM + tid] = Darr[HDIM + tid]; }
    float ctxr = 0.f;                      // ctx[my batch][col]
    if (tid < 2) { ld_dec[tid][0] = 0.f; ld_dec[tid][1] = 0.f; ld_dec[tid][2] = 1.f; }
    __syncthreads();

    for (int i = 0; i < TSTEPS; ++i) {
        // ---- decoder input projection (half/col mapping) ----
        float dpv = fmaf(ld_dec[half][0], w0,
                     fmaf(ld_dec[half][1], w1,
                      fmaf(ld_dec[half][2], w2, inb_t)));
        __syncthreads();                   // ld_dec consumed; xd safe to write
        ld_xd[half * HDIM + col] = dpv;
        __syncthreads();

        #pragma unroll 1
        for (int blk = 0; blk < 2; ++blk) {
            // ---- S4 state update + gelu for BOTH batches ----
            {
                float* s0p = blk ? sB0 : sA0;
                float* s1p = blk ? sB1 : sA1;
                const float* Ar = blk ? A1 : A0;
                const float* Br = blk ? B1 : B0;
                const float* Cr = blk ? C1 : C0;
                const float* Dl = ld_D + blk * HDIM;
                #pragma unroll
                for (int k = 0; k < 8; ++k) {
                    int h = hg + 64 * k;
                    float xh0 = ld_xd[h];
                    float xh1 = ld_xd[HDIM + h];
                    float sv0 = fmaf(Ar[k], s0p[k], Br[k] * xh0);
                    float sv1 = fmaf(Ar[k], s1p[k], Br[k] * xh1);
                    s0p[k] = sv0; s1p[k] = sv1;
                    float p0 = sv0 * Cr[k];
                    float p1 = sv1 * Cr[k];
                    p0 += __shfl_xor(p0, 1);  p1 += __shfl_xor(p1, 1);
                    p0 += __shfl_xor(p0, 2);  p1 += __shfl_xor(p1, 2);
                    p0 += __shfl_xor(p0, 4);  p1 += __shfl_xor(p1, 4);
                    p0 += __shfl_xor(p0, 8);  p1 += __shfl_xor(p1, 8);
                    if (n == 0) {
                        float dh = Dl[h];
                        ld_g0[h] = gelu_f32(p0 + dh * xh0);
                        ld_g1[h] = gelu_f32(p1 + dh * xh1);
                    }
                }
            }
            __syncthreads();
            // ---- matvec: rows hq*64..+63 (rotated pairs), 4 cols, 2 batches ----
            {
                const float4* Wb = (const float4*)outW
                                 + (size_t)blk * HDIM * 128
                                 + (size_t)(hq * 64) * 128 + cq;
                const float* g0l = ld_g0 + hq * 64;
                const float* g1l = ld_g1 + hq * 64;
                float4 acc0 = make_float4(0.f, 0.f, 0.f, 0.f);
                float4 acc1 = make_float4(0.f, 0.f, 0.f, 0.f);
                #pragma unroll 4
                for (int c = 0; c < 32; ++c) {
                    int r = 2 * ((rotp + c) & 31);
                    float4 wa = Wb[(size_t)r * 128];
                    float4 wb = Wb[(size_t)(r + 1) * 128];
                    float g00 = g0l[r], g01 = g0l[r + 1];
                    float g10 = g1l[r], g11 = g1l[r + 1];
                    acc0.x = fmaf(g01, wb.x, fmaf(g00, wa.x, acc0.x));
                    acc0.y = fmaf(g01, wb.y, fmaf(g00, wa.y, acc0.y));
                    acc0.z = fmaf(g01, wb.z, fmaf(g00, wa.z, acc0.z));
                    acc0.w = fmaf(g01, wb.w, fmaf(g00, wa.w, acc0.w));
                    acc1.x = fmaf(g11, wb.x, fmaf(g10, wa.x, acc1.x));
                    acc1.y = fmaf(g11, wb.y, fmaf(g10, wa.y, acc1.y));
                    acc1.z = fmaf(g11, wb.z, fmaf(g10, wa.z, acc1.z));
                    acc1.w = fmaf(g11, wb.w, fmaf(g10, wa.w, acc1.w));
                }
                *(float4*)&ld_z[(0 * 8 + hq) * HDIM + 4 * cq] = acc0;
                *(float4*)&ld_z[(1 * 8 + hq) * HDIM + 4 * cq] = acc1;
            }
            __syncthreads();
            // ---- z-sum + residual + one-pass LN (half/col mapping) ----
            {
                const float* zb = ld_z + half * 8 * HDIM + col;
                float z = zb[0] + zb[HDIM] + zb[2 * HDIM] + zb[3 * HDIM]
                        + zb[4 * HDIM] + zb[5 * HDIM] + zb[6 * HDIM] + zb[7 * HDIM]
                        + outb[blk * HDIM + col];
                float res = (i == 0) ? dpv : z;    // ref: residual=proj @ i==0
                float tmp = z + res;
                float v1 = tmp, v2 = tmp * tmp;
                #pragma unroll
                for (int m = 1; m < 64; m <<= 1) {
                    v1 += __shfl_xor(v1, m);
                    v2 += __shfl_xor(v2, m);
                }
                int wave = tid >> 6;               // waves 0-7: batch0, 8-15: batch1
                if ((tid & 63) == 0) { ld_red[2 * wave] = v1; ld_red[2 * wave + 1] = v2; }
                __syncthreads();
                float s1r = 0.f, s2r = 0.f;
                #pragma unroll
                for (int q = 0; q < 8; ++q) {
                    s1r += ld_red[2 * (half * 8 + q)];
                    s2r += ld_red[2 * (half * 8 + q) + 1];
                }
                float mu  = s1r * (1.f / 512.f);
                float var = s2r * (1.f / 512.f) - mu * mu;
                float rs  = rsqrtf(var + 1e-5f);
                float xn  = (tmp - mu) * rs * ln_g[blk * HDIM + col]
                          + ln_b[blk * HDIM + col];
                __syncthreads();                   // red consumed
                ld_xd[half * HDIM + col] = xn;
                __syncthreads();
            }
        }

        // ================= head #1 (both batches in parallel) =================
        {
            float v = ld_xd[half * HDIM + col] + ctxr;
            const float* w = headW + col * ODIM;
            float p[ODIM];
            #pragma unroll
            for (int o = 0; o < ODIM; ++o) p[o] = v * w[o];
            #pragma unroll
            for (int m = 1; m < 64; m <<= 1) {
                #pragma unroll
                for (int o = 0; o < ODIM; ++o) p[o] += __shfl_xor(p[o], m);
            }
            int wave = tid >> 6;
            if ((tid & 63) == 0) {
                #pragma unroll
                for (int o = 0; o < ODIM; ++o) ld_hred[wave * ODIM + o] = p[o];
            }
            __syncthreads();
            if (col < ODIM) {
                float s = headb[col];
                #pragma unroll
                for (int wv = 0; wv < 8; ++wv) s += ld_hred[(half * 8 + wv) * ODIM + col];
                ld_logit[half][col] = s;
            }
            __syncthreads();
        }

        const bool is_out = ((i & 1) == 0);
        if (is_out) {
            if (col < ODIM)
                out[((b0 + half) * TSTEPS + i) * ODIM + col] = sig32(ld_logit[half][col]);
            if (col == 0) {    // tids 0 and 512 (different waves)
                float nc = (sig32(ld_logit[half][0]) > 0.5f) ? 1.f : 0.f;
                ld_dec[half][0] = nc; ld_dec[half][1] = 1.f; ld_dec[half][2] = 0.f;
            }
            __syncthreads();
        } else {
            // np.argmax over f32 SIGMOIDS (saturation => not logit-argmax!)
            if (col == 0) {
                int best = 0; float bv = sig32(ld_logit[half][3]);
                #pragma unroll
                for (int o = 1; o < 6; ++o) {
                    float v2 = sig32(ld_logit[half][3 + o]);
                    if (v2 > bv) { bv = v2; best = o; }
                }
                ld_ptr[half] = best;
                ld_dec[half][0] = 0.f; ld_dec[half][1] = 0.f; ld_dec[half][2] = 1.f;
            }
            __syncthreads();
            {   // ctx += encoded[b, ptr, :]
                const float* iseq = input_seq + ((b0 + half) * SEQ + ld_ptr[half]) * 3;
                ctxr += fmaf(iseq[0], w0, fmaf(iseq[1], w1, fmaf(iseq[2], w2, inb_t)));
            }
            // ================= head #2 =================
            {
                float v = ld_xd[half * HDIM + col] + ctxr;
                const float* w = headW + col * ODIM;
                float p[ODIM];
                #pragma unroll
                for (int o = 0; o < ODIM; ++o) p[o] = v * w[o];
                #pragma unroll
                for (int m = 1; m < 64; m <<= 1) {
                    #pragma unroll
                    for (int o = 0; o < ODIM; ++o) p[o] += __shfl_xor(p[o], m);
                }
                int wave = tid >> 6;
                if ((tid & 63) == 0) {
                    #pragma unroll
                    for (int o = 0; o < ODIM; ++o) ld_hred[wave * ODIM + o] = p[o];
                }
                __syncthreads();
                if (col < ODIM) {
                    float s = headb[col];
                    #pragma unroll
                    for (int wv = 0; wv < 8; ++wv)
                        s += ld_hred[(half * 8 + wv) * ODIM + col];
                    out[((b0 + half) * TSTEPS + i) * ODIM + col] = sig32(s);
                }
                __syncthreads();   // hred/xd consumed before next step
            }
        }
    }
}

extern "C" void kernel_launch(void* const* d_in, const int* in_sizes, int n_in,
                              void* d_out, int out_size, void* d_ws, size_t ws_size,
                              hipStream_t stream) {
    (void)in_sizes; (void)n_in; (void)d_ws; (void)ws_size; (void)out_size;
    const float* input_seq = (const float*)d_in[0];
    // d_in[1] = autoregressive_steps (scalar) -- T fixed at 63 by the model
    const float* in_W   = (const float*)d_in[2];
    const float* in_b   = (const float*)d_in[3];
    const float* Aarr   = (const float*)d_in[4];
    const float* Barr   = (const float*)d_in[5];
    const float* Carr   = (const float*)d_in[6];
    const float* Darr   = (const float*)d_in[7];
    const float* outW   = (const float*)d_in[8];
    const float* outb   = (const float*)d_in[9];
    const float* ln_g   = (const float*)d_in[10];
    const float* ln_b   = (const float*)d_in[11];
    const float* headW  = (const float*)d_in[12];
    const float* headb  = (const float*)d_in[13];
    float* out = (float*)d_out;

    s4_decode_kernel<<<NWG, NTHR, 0, stream>>>(
        input_seq, in_W, in_b, Aarr, Barr, Carr, Darr,
        outW, outb, ln_g, ln_b, headW, headb, out);
}